// Round 1
// 172.573 us; speedup vs baseline: 1.0020x; 1.0020x over previous
//
#include <hip/hip_runtime.h>
#include <math.h>

#define NB   2
#define CIN  256
#define NN   6400
#define CKd  64
#define CVd  128
#define COd  256

using bf16   = __bf16;
using bf16x4 = __attribute__((ext_vector_type(4))) bf16;
using bf16x8 = __attribute__((ext_vector_type(8))) bf16;
using f32x4  = __attribute__((ext_vector_type(4))) float;

__device__ __forceinline__ void lds_cp16(const void* g, void* l) {
    __builtin_amdgcn_global_load_lds((const __attribute__((address_space(1))) void*)g,
                                     (__attribute__((address_space(3))) void*)l, 16, 0, 0);
}

// ---------------------------------------------------------------------------
// Fold BN into bf16 weights + fp32 biases.  q weights/bias pre-scaled by
// 0.125*log2(e) so attn softmax is p = exp2(s + c).
// ---------------------------------------------------------------------------
__global__ void prep_kernel(const float* __restrict__ fk_w, const float* __restrict__ fk_g,
                            const float* __restrict__ fk_b, const float* __restrict__ fk_m,
                            const float* __restrict__ fk_v,
                            const float* __restrict__ fq_w, const float* __restrict__ fq_g,
                            const float* __restrict__ fq_b, const float* __restrict__ fq_m,
                            const float* __restrict__ fq_v,
                            const float* __restrict__ fv_w, const float* __restrict__ fv_b,
                            const float* __restrict__ W_w,  const float* __restrict__ W_b,
                            bf16* __restrict__ wkb, bf16* __restrict__ wqb,
                            bf16* __restrict__ wvb, bf16* __restrict__ wob,
                            float* __restrict__ bias)
{
    const int idx = blockIdx.x * 256 + threadIdx.x;
    const float QS = 0.18033688011112042f;   // 0.125 * log2(e)
    if (idx < 16384) {
        const int co = idx >> 8;
        const float a = fk_g[co] * rsqrtf(fk_v[co] + 1e-5f);
        wkb[idx] = (bf16)(fk_w[idx] * a);
    } else if (idx < 32768) {
        const int i = idx - 16384, co = i >> 8;
        const float a = fq_g[co] * rsqrtf(fq_v[co] + 1e-5f) * QS;
        wqb[i] = (bf16)(fq_w[i] * a);
    } else if (idx < 65536) {
        const int i = idx - 32768;
        wvb[i] = (bf16)fv_w[i];
    } else if (idx < 98304) {
        const int i = idx - 65536;
        wob[i] = (bf16)W_w[i];
    } else if (idx < 98816) {
        const int j = idx - 98304;
        if (j < 64)       { const float a = fk_g[j] * rsqrtf(fk_v[j] + 1e-5f); bias[j] = fk_b[j] - fk_m[j] * a; }
        else if (j < 128) { const int c = j - 64; const float a = fq_g[c] * rsqrtf(fq_v[c] + 1e-5f); bias[j] = (fq_b[c] - fq_m[c] * a) * QS; }
        else if (j < 256) bias[j] = fv_b[j - 128];
        else              bias[j] = W_b[j - 256];
    }
}

// ---------------------------------------------------------------------------
// k/q/v projection, NEW r15: split-K two-pass staging (128 c per pass) halves
// LDS 64KB -> 32KB so 4 blocks/CU co-reside (was 2): the 800-block grid now
// fits a single dispatch round (1024 slots) instead of 1.56 rounds.
// Same fused transpose+cvt register path per half.  grid (100, 4, NB).
// ---------------------------------------------------------------------------
__launch_bounds__(256, 4)
__global__ void projkqv_kernel(const float* __restrict__ x, const float* __restrict__ y,
                               const bf16* __restrict__ wkb, const bf16* __restrict__ wqb,
                               const bf16* __restrict__ wvb, const float* __restrict__ bias,
                               bf16* __restrict__ kb, bf16* __restrict__ qb, bf16* __restrict__ vb)
{
    __shared__ __align__(16) bf16 sbuf[64 * 128];   // 16 KB src [n][c-half], XOR chunks
    __shared__ __align__(16) bf16 wbuf[64 * 128];   // 16 KB weights half, XOR chunks

    const int tid  = threadIdx.x;
    const int lane = tid & 63, wav = tid >> 6;
    const int l15  = lane & 15, quad = lane >> 4;
    const int b    = blockIdx.z, m = blockIdx.y;
    const int n0   = blockIdx.x * 64;

    const float* srcg = ((m == 0) ? x : y) + (size_t)b * CIN * NN;
    const bf16* wg    = (m == 0) ? wkb : (m == 1) ? wqb : (wvb + (size_t)(m - 2) * 64 * CIN);

    const int key = l15 & 7;
    f32x4 acc[4];
#pragma unroll
    for (int j = 0; j < 4; ++j) acc[j] = (f32x4){0.f, 0.f, 0.f, 0.f};

    for (int p = 0; p < 2; ++p) {
        if (p) __syncthreads();            // all waves done reading pass-0 bufs

        // weights half DMA: 64 rows x 128 c (256B/row, 4 rows per cp16)
        {
            const int r4  = lane >> 4;
            const int c16 = lane & 15;
#pragma unroll
            for (int i = 0; i < 4; ++i) {
                const int rg = wav * 16 + i * 4;
                const int r  = rg + r4;
                const int cs = c16 ^ (r & 7);
                lds_cp16(wg + (size_t)r * 256 + p * 128 + cs * 8, &wbuf[rg * 128]);
            }
        }
        // src half: load + cvt + packed b128 scatter (register transpose)
        {
            const int nl = (tid & 15) * 4;
            const int cq = tid >> 4;            // 0..15 local chunk
            const int cb = p * 128 + cq * 8;
            float4 v[8];
#pragma unroll
            for (int e = 0; e < 8; ++e)
                v[e] = *(const float4*)(srcg + (size_t)(cb + e) * NN + n0 + nl);
#pragma unroll
            for (int i = 0; i < 4; ++i) {
                const int n = nl + i;
                bf16x8 pk;
#pragma unroll
                for (int e = 0; e < 8; ++e) pk[e] = (bf16)(&v[e].x)[i];
                *(bf16x8*)&sbuf[n * 128 + ((cq ^ (n & 7)) * 8)] = pk;
            }
        }
        __syncthreads();                   // drain DMA + ds_writes

        if (m < 2) {
            const int arow = wav * 16 + l15;
#pragma unroll
            for (int k4 = 0; k4 < 16; k4 += 4) {
                const bf16x8 af = *(const bf16x8*)&sbuf[arow * 128 + (((k4 + quad) ^ key) * 8)];
#pragma unroll
                for (int nt = 0; nt < 4; ++nt) {
                    const int brow = nt * 16 + l15;
                    const bf16x8 bfw = *(const bf16x8*)&wbuf[brow * 128 + (((k4 + quad) ^ key) * 8)];
                    acc[nt] = __builtin_amdgcn_mfma_f32_16x16x32_bf16(af, bfw, acc[nt], 0, 0, 0);
                }
            }
        } else {
            const int arow = wav * 16 + l15;
#pragma unroll
            for (int k4 = 0; k4 < 16; k4 += 4) {
                const bf16x8 af = *(const bf16x8*)&wbuf[arow * 128 + (((k4 + quad) ^ key) * 8)];
#pragma unroll
                for (int nt = 0; nt < 4; ++nt) {
                    const int brow = nt * 16 + l15;
                    const bf16x8 bfy = *(const bf16x8*)&sbuf[brow * 128 + (((k4 + quad) ^ key) * 8)];
                    acc[nt] = __builtin_amdgcn_mfma_f32_16x16x32_bf16(af, bfy, acc[nt], 0, 0, 0);
                }
            }
        }
    }

    if (m < 2) {
        const float* bs = bias + m * 64;
        bf16* dst = (m == 0) ? kb : qb;
        const int nb = n0 + wav * 16;
#pragma unroll
        for (int nt = 0; nt < 4; ++nt) {
            const float bv = bs[nt * 16 + l15];
#pragma unroll
            for (int r = 0; r < 4; ++r) {
                const int n = nb + quad * 4 + r;
                dst[((size_t)b * NN + n) * CKd + nt * 16 + l15] = (bf16)(acc[nt][r] + bv);
            }
        }
    } else {
        const int cv0 = (m - 2) * 64 + wav * 16;
#pragma unroll
        for (int r = 0; r < 4; ++r) {
            const int cv = cv0 + quad * 4 + r;
            const float bv = bias[128 + cv];
#pragma unroll
            for (int nt = 0; nt < 4; ++nt)
                vb[((size_t)b * CVd + cv) * NN + n0 + nt * 16 + l15] = (bf16)(acc[nt][r] + bv);
        }
    }
}

// ---------------------------------------------------------------------------
// Flash attention, NEW r15 (from r11/r13 base, counters: Mfma 22 / VALU 44 /
// idle ~34 -> pipe-serialized within wave):
//  (1) softmax constant folded into MFMA C-init (z = -11.54) -> kills 64
//      v_sub per iter.
//  (2) p_lds gains a [ph] dim (64->80 KB LDS, still exactly 2 blocks/CU):
//      removes the r14 aliasing hazard, enabling
//  (3) hand-interleave of softmax(ph1) VALU with PV(ph0) MFMA so the wave
//      feeds both pipes concurrently.
//  (4) s_setprio(1) around pure-MFMA clusters (m191 precedent).
// Sync structure (1 barrier/iter, double-buffered K/V DMA) untouched.
// ---------------------------------------------------------------------------
__launch_bounds__(256, 2)
__global__ void attn_kernel(const bf16* __restrict__ qb, const bf16* __restrict__ kb,
                            const bf16* __restrict__ vb,
                            bf16* __restrict__ pO, float* __restrict__ pl, int KS)
{
    __shared__ __align__(16) bf16 kbuf[2][64 * 64];           // 16 KB
    __shared__ __align__(16) bf16 vbuf[2][128 * 64];          // 32 KB
    __shared__ __align__(16) bf16 p_lds[4][2][2][16][64];     // 32 KB  [wave][ph][qtl]

    const int lane = threadIdx.x & 63;
    const int wav  = threadIdx.x >> 6;
    const int l15  = lane & 15;
    const int quad = lane >> 4;
    const int r8   = lane >> 3;
    const int c_src = (lane & 7) ^ r8;
    const int sw   = l15 & 7;
    const int pkey = (l15 & 7) << 1;

    const int id    = blockIdx.x;
    const int ks    = id % KS;
    const int rst   = id / KS;
    const int b     = rst & 1;
    const int qtile = rst >> 1;
    const int q0    = qtile * 256 + wav * 64;

    const bf16* qrow = qb + (size_t)b * NN * CKd;
    const bf16* krow = kb + (size_t)b * NN * CKd;
    const bf16* vrow = vb + (size_t)b * CVd * NN;

    bf16x8 qf[4][2];
#pragma unroll
    for (int qt = 0; qt < 4; ++qt)
#pragma unroll
        for (int s = 0; s < 2; ++s)
            qf[qt][s] = *(const bf16x8*)(qrow + (size_t)(q0 + qt * 16 + l15) * CKd + s * 32 + quad * 8);

    const float ZC = -11.541560327111707f;
    const f32x4 zini = (f32x4){ZC, ZC, ZC, ZC};

    f32x4 acc[4][8];
#pragma unroll
    for (int qt = 0; qt < 4; ++qt)
#pragma unroll
        for (int cv = 0; cv < 8; ++cv) acc[qt][cv] = (f32x4){0.f, 0.f, 0.f, 0.f};
    float psum[4] = {0.f, 0.f, 0.f, 0.f};

    const int t0 = (100 * ks) / KS;
    const int nt = (100 * (ks + 1)) / KS - t0;

    auto stage = [&](int t, int bi) {
        const int key0 = t * 64;
        lds_cp16(krow + (size_t)(key0 + wav * 8 + r8) * CKd + c_src * 8,
                 &kbuf[bi][(wav * 8) * 64]);
        lds_cp16(krow + (size_t)(key0 + (wav + 4) * 8 + r8) * CKd + c_src * 8,
                 &kbuf[bi][((wav + 4) * 8) * 64]);
#pragma unroll
        for (int g4 = 0; g4 < 4; ++g4) {
            const int g = wav * 4 + g4;
            lds_cp16(vrow + (size_t)(g * 8 + r8) * NN + key0 + c_src * 8,
                     &vbuf[bi][(g * 8) * 64]);
        }
    };

    stage(t0, 0);   // prologue

    for (int t = 0; t < nt; ++t) {
        __syncthreads();                    // drains DMA(t); guards buf reuse
        if (t + 1 < nt) stage(t0 + t + 1, (t + 1) & 1);
        const bf16* kcur = &kbuf[t & 1][0];
        const bf16* vcur = &vbuf[t & 1][0];

        f32x4 s4[2][4];

        // ---- QK^T ph0: S^T = K * Q^T, C-init = softmax constant ----
        __builtin_amdgcn_s_setprio(1);
#pragma unroll
        for (int kt = 0; kt < 4; ++kt) {
            const int rr = kt * 16 + l15;
            const bf16x8 kf0 = *(const bf16x8*)&kcur[rr * 64 + ((quad ^ sw) * 8)];
            const bf16x8 kf1 = *(const bf16x8*)&kcur[rr * 64 + (((4 + quad) ^ sw) * 8)];
#pragma unroll
            for (int qtl = 0; qtl < 2; ++qtl) {
                f32x4 z = zini;
                z = __builtin_amdgcn_mfma_f32_16x16x32_bf16(kf0, qf[qtl][0], z, 0, 0, 0);
                z = __builtin_amdgcn_mfma_f32_16x16x32_bf16(kf1, qf[qtl][1], z, 0, 0, 0);
                s4[qtl][kt] = z;
            }
        }
        __builtin_amdgcn_s_setprio(0);

        // ---- softmax ph0 -> p_lds[.][0][.] ----
#pragma unroll
        for (int qtl = 0; qtl < 2; ++qtl) {
            float ps = 0.f;
#pragma unroll
            for (int kt = 0; kt < 4; ++kt) {
                bf16x4 pk;
#pragma unroll
                for (int r = 0; r < 4; ++r) {
                    const float p = exp2f(s4[qtl][kt][r]);
                    ps += p;
                    pk[r] = (bf16)p;
                }
                *(bf16x4*)&p_lds[wav][0][qtl][l15][((kt * 4 + quad) ^ pkey) * 4] = pk;
            }
            psum[qtl] += ps;
        }

        // ---- QK^T ph1 (s4 reused) ----
        __builtin_amdgcn_s_setprio(1);
#pragma unroll
        for (int kt = 0; kt < 4; ++kt) {
            const int rr = kt * 16 + l15;
            const bf16x8 kf0 = *(const bf16x8*)&kcur[rr * 64 + ((quad ^ sw) * 8)];
            const bf16x8 kf1 = *(const bf16x8*)&kcur[rr * 64 + (((4 + quad) ^ sw) * 8)];
#pragma unroll
            for (int qtl = 0; qtl < 2; ++qtl) {
                f32x4 z = zini;
                z = __builtin_amdgcn_mfma_f32_16x16x32_bf16(kf0, qf[2 + qtl][0], z, 0, 0, 0);
                z = __builtin_amdgcn_mfma_f32_16x16x32_bf16(kf1, qf[2 + qtl][1], z, 0, 0, 0);
                s4[qtl][kt] = z;
            }
        }
        __builtin_amdgcn_s_setprio(0);

        // ---- PV ph0 (MFMA) interleaved with softmax ph1 (VALU) ----
        // distinct p_lds[ph] slots -> no aliasing serialization (r14 fix)
        {
            bf16x8 pfA, pfB;
#pragma unroll
            for (int u = 0; u < 8; ++u) {
                const int sp = u >> 2;
                if ((u & 3) == 0) {
                    pfA = *(const bf16x8*)&p_lds[wav][0][0][l15][((sp * 8 + quad * 2) ^ pkey) * 4];
                    pfB = *(const bf16x8*)&p_lds[wav][0][1][l15][((sp * 8 + quad * 2) ^ pkey) * 4];
                }
                {   // softmax ph1, chunk u: (qtl = u>>2, kt = u&3)
                    const int qtl = u >> 2, kt = u & 3;
                    bf16x4 pk;
                    float ps = 0.f;
#pragma unroll
                    for (int r = 0; r < 4; ++r) {
                        const float p = exp2f(s4[qtl][kt][r]);
                        ps += p;
                        pk[r] = (bf16)p;
                    }
                    *(bf16x4*)&p_lds[wav][1][qtl][l15][((kt * 4 + quad) ^ pkey) * 4] = pk;
                    psum[2 + qtl] += ps;
                }
#pragma unroll
                for (int v2 = 0; v2 < 2; ++v2) {   // PV ph0: two cv subtiles
                    const int cvt = (u & 3) * 2 + v2;
                    const int rr = cvt * 16 + l15;
                    const bf16x8 vf = *(const bf16x8*)&vcur[rr * 64 + (((sp * 4 + quad) ^ sw) * 8)];
                    acc[0][cvt] = __builtin_amdgcn_mfma_f32_16x16x32_bf16(vf, pfA, acc[0][cvt], 0, 0, 0);
                    acc[1][cvt] = __builtin_amdgcn_mfma_f32_16x16x32_bf16(vf, pfB, acc[1][cvt], 0, 0, 0);
                }
            }
        }

        // ---- PV ph1 ----
        __builtin_amdgcn_s_setprio(1);
#pragma unroll
        for (int sp = 0; sp < 2; ++sp) {
            const bf16x8 pf0 = *(const bf16x8*)&p_lds[wav][1][0][l15][((sp * 8 + quad * 2) ^ pkey) * 4];
            const bf16x8 pf1 = *(const bf16x8*)&p_lds[wav][1][1][l15][((sp * 8 + quad * 2) ^ pkey) * 4];
#pragma unroll
            for (int cvt = 0; cvt < 8; ++cvt) {
                const int rr = cvt * 16 + l15;
                const bf16x8 vf = *(const bf16x8*)&vcur[rr * 64 + (((sp * 4 + quad) ^ sw) * 8)];
                acc[2][cvt] = __builtin_amdgcn_mfma_f32_16x16x32_bf16(vf, pf0, acc[2][cvt], 0, 0, 0);
                acc[3][cvt] = __builtin_amdgcn_mfma_f32_16x16x32_bf16(vf, pf1, acc[3][cvt], 0, 0, 0);
            }
        }
        __builtin_amdgcn_s_setprio(0);
    }

    // ---- epilogue: transpose acc through LDS -> coalesced pO stores ----
    __syncthreads();
    bf16* tbuf = &p_lds[wav][0][0][0][0];   // per-wave 4096 bf16, use [16][128]
    const size_t pb = (size_t)ks * NB + b;
#pragma unroll
    for (int qt = 0; qt < 4; ++qt) {
        psum[qt] += __shfl_xor(psum[qt], 16);
        psum[qt] += __shfl_xor(psum[qt], 32);
#pragma unroll
        for (int cvt = 0; cvt < 8; ++cvt) {
            bf16x4 pk;
#pragma unroll
            for (int r = 0; r < 4; ++r) pk[r] = (bf16)acc[qt][cvt][r];
            const int u = (cvt * 4 + quad) ^ (l15 << 1);
            *(bf16x4*)&tbuf[l15 * 128 + u * 4] = pk;
        }
#pragma unroll
        for (int j = 0; j < 4; ++j) {
            const int row = j * 4 + (lane >> 4);
            const int g   = ((lane & 15) * 2) ^ ((row & 15) << 1);
            const bf16x8 vv = *(const bf16x8*)&tbuf[row * 128 + g * 4];
            *(bf16x8*)(pO + (pb * NN + q0 + qt * 16) * CVd + j * 512 + lane * 8) = vv;
        }
        if (quad == 0) pl[pb * NN + q0 + qt * 16 + l15] = psum[qt];
    }
}

// ---------------------------------------------------------------------------
// Fused combine + output projection, NEW r15:
//  - phase-1 KS chunk accumulation gets 1-deep prefetch (was a serial
//    ~900-cycle HBM latency chain per ksi).
//  - wbuf split into two 128-co passes (72KB -> 40KB LDS -> 4 blocks/CU);
//    half-1 DMA issued before half-0 stores so it overlaps.
//  - Lrow LDS buffer dropped: every thread sums its own pl row.
// out = gamma*(W.ctx + W_b) + x.  grid (200, NB).
// ---------------------------------------------------------------------------
__launch_bounds__(256, 4)
__global__ void outproj_kernel(const bf16* __restrict__ pO, const float* __restrict__ pl,
                               const bf16* __restrict__ wob, const float* __restrict__ bias,
                               const float* __restrict__ x, const float* __restrict__ gam,
                               float* __restrict__ out, int KS)
{
    __shared__ __align__(16) bf16 wbuf[128 * 128];   // 32 KB (co half)
    __shared__ __align__(16) bf16 cbuf[32 * 128];    // 8 KB

    const int tid  = threadIdx.x;
    const int lane = tid & 63, wav = tid >> 6;
    const int l15  = lane & 15, quad = lane >> 4;
    const int b    = blockIdx.y;
    const int n0   = blockIdx.x * 32;

    auto stage_w = [&](int p) {
        const int r4 = lane >> 4;
        const int c  = lane & 15;
#pragma unroll
        for (int i = 0; i < 8; ++i) {
            const int rg = wav * 32 + i * 4;
            const int r  = rg + r4;
            const int cs = c ^ (r & 7);
            lds_cp16(wob + (size_t)(p * 128 + r) * CVd + cs * 8, &wbuf[rg * 128]);
        }
    };
    stage_w(0);

    // ---- phase 1: accumulate KS chunks of pO, 16 vals/thread, prefetched ----
    const int tn = tid >> 3;
    const int tc = (tid & 7) * 16;
    const size_t kstr = (size_t)NB * NN * CVd;
    const bf16* src0 = pO + ((size_t)b * NN + n0 + tn) * CVd + tc;
    float vacc[16];
#pragma unroll
    for (int i = 0; i < 16; ++i) vacc[i] = 0.f;
    float L = 0.f;

    bf16x8 c0 = *(const bf16x8*)(src0);
    bf16x8 c1 = *(const bf16x8*)(src0 + 8);
    for (int ksi = 0; ksi < KS; ++ksi) {
        bf16x8 nx0 = c0, nx1 = c1;
        if (ksi + 1 < KS) {
            const bf16* s = src0 + (size_t)(ksi + 1) * kstr;
            nx0 = *(const bf16x8*)(s);
            nx1 = *(const bf16x8*)(s + 8);
        }
        L += pl[(size_t)(ksi * NB + b) * NN + n0 + tn];
#pragma unroll
        for (int e = 0; e < 8; ++e) vacc[e]     += (float)c0[e];
#pragma unroll
        for (int e = 0; e < 8; ++e) vacc[8 + e] += (float)c1[e];
        c0 = nx0; c1 = nx1;
    }
    {
        const float rL = 1.0f / L;
#pragma unroll
        for (int j = 0; j < 2; ++j) {
            bf16x8 o;
#pragma unroll
            for (int e = 0; e < 8; ++e) o[e] = (bf16)(vacc[j * 8 + e] * rL);
            const int c = (tid & 7) * 2 + j;
            *(bf16x8*)&cbuf[tn * 128 + ((c ^ (tn & 7)) * 8)] = o;
        }
    }
    __syncthreads();   // drains wbuf half-0 DMA + cbuf writes

    const float gm = gam[0];

    auto mfma_pass = [&](f32x4 (&acc)[2][2]) {
#pragma unroll
        for (int i = 0; i < 2; ++i)
#pragma unroll
            for (int j = 0; j < 2; ++j) acc[i][j] = (f32x4){0.f, 0.f, 0.f, 0.f};
#pragma unroll
        for (int kk = 0; kk < 4; ++kk) {
#pragma unroll
            for (int cot = 0; cot < 2; ++cot) {
                const int arow = wav * 32 + cot * 16 + l15;
                const bf16x8 af = *(const bf16x8*)&wbuf[arow * 128 + (((kk * 4 + quad) ^ (arow & 7)) * 8)];
#pragma unroll
                for (int nt = 0; nt < 2; ++nt) {
                    const int brow = nt * 16 + l15;
                    const bf16x8 bfc = *(const bf16x8*)&cbuf[brow * 128 + (((kk * 4 + quad) ^ (brow & 7)) * 8)];
                    acc[cot][nt] = __builtin_amdgcn_mfma_f32_16x16x32_bf16(af, bfc, acc[cot][nt], 0, 0, 0);
                }
            }
        }
    };
    auto store_pass = [&](const f32x4 (&acc)[2][2], int p) {
#pragma unroll
        for (int cot = 0; cot < 2; ++cot)
#pragma unroll
            for (int r = 0; r < 4; ++r) {
                const int co = p * 128 + wav * 32 + cot * 16 + quad * 4 + r;
                const float bv = bias[256 + co];
#pragma unroll
                for (int nt = 0; nt < 2; ++nt) {
                    const int n = n0 + nt * 16 + l15;
                    const size_t a = ((size_t)b * COd + co) * NN + n;
                    out[a] = gm * (acc[cot][nt][r] + bv) + x[a];
                }
            }
    };

    f32x4 acc0[2][2];
    mfma_pass(acc0);
    __syncthreads();          // all waves done reading wbuf half 0
    stage_w(1);               // issue half-1 DMA ...
    store_pass(acc0, 0);      // ... overlapped with half-0 stores
    __syncthreads();          // drain half-1 DMA
    f32x4 acc1[2][2];
    mfma_pass(acc1);
    store_pass(acc1, 1);
}

// ---------------------------------------------------------------------------
extern "C" void kernel_launch(void* const* d_in, const int* in_sizes, int n_in,
                              void* d_out, int out_size, void* d_ws, size_t ws_size,
                              hipStream_t stream)
{
    const float* x     = (const float*)d_in[0];
    const float* y     = (const float*)d_in[1];
    const float* fk_w  = (const float*)d_in[2];
    const float* fk_g  = (const float*)d_in[3];
    const float* fk_b  = (const float*)d_in[4];
    const float* fk_m  = (const float*)d_in[5];
    const float* fk_v  = (const float*)d_in[6];
    const float* fq_w  = (const float*)d_in[7];
    const float* fq_g  = (const float*)d_in[8];
    const float* fq_b  = (const float*)d_in[9];
    const float* fq_m  = (const float*)d_in[10];
    const float* fq_v  = (const float*)d_in[11];
    const float* fv_w  = (const float*)d_in[12];
    const float* fv_b  = (const float*)d_in[13];
    const float* W_w   = (const float*)d_in[14];
    const float* W_b   = (const float*)d_in[15];
    const float* gamma = (const float*)d_in[16];
    float* out = (float*)d_out;

    char* ws = (char*)d_ws;
    size_t off = 0;
    auto carve = [&](size_t bytes) -> char* {
        char* p = ws + off;
        off = (off + bytes + 255) & ~(size_t)255;
        return p;
    };

    bf16*  kb   = (bf16*)carve((size_t)NB * NN * CKd * 2);
    bf16*  qbuf = (bf16*)carve((size_t)NB * NN * CKd * 2);
    bf16*  vb   = (bf16*)carve((size_t)NB * CVd * NN * 2);
    bf16*  wkb  = (bf16*)carve((size_t)CKd * CIN * 2);
    bf16*  wqb  = (bf16*)carve((size_t)CKd * CIN * 2);
    bf16*  wvb  = (bf16*)carve((size_t)CVd * CIN * 2);
    bf16*  wob  = (bf16*)carve((size_t)COd * CVd * 2);
    float* bias = (float*)carve(512 * 4);

    const size_t region = ws_size - off;
    const size_t per_ks = (size_t)NB * NN * CVd * 2 + (size_t)NB * NN * 4 + 512;
    int KS = 1;
    {
        const int cand[6] = {10, 8, 5, 4, 2, 1};
        for (int i = 0; i < 6; ++i)
            if ((size_t)cand[i] * per_ks <= region) { KS = cand[i]; break; }
    }
    bf16*  pO = (bf16*)carve((size_t)KS * NB * NN * CVd * 2);
    float* pl = (float*)carve((size_t)KS * NB * NN * 4);

    const dim3 blk(256);
    prep_kernel<<<386, blk, 0, stream>>>(fk_w, fk_g, fk_b, fk_m, fk_v,
                                         fq_w, fq_g, fq_b, fq_m, fq_v,
                                         fv_w, fv_b, W_w, W_b,
                                         wkb, wqb, wvb, wob, bias);
    projkqv_kernel<<<dim3(100, 4, NB), blk, 0, stream>>>(x, y, wkb, wqb, wvb, bias, kb, qbuf, vb);
    attn_kernel<<<dim3(25 * NB * KS), blk, 0, stream>>>(qbuf, kb, vb, pO, pl, KS);
    outproj_kernel<<<dim3(200, NB), blk, 0, stream>>>(pO, pl, wob, bias, x, gamma, out, KS);
}

// Round 2
// 170.949 us; speedup vs baseline: 1.0115x; 1.0095x over previous
//
#include <hip/hip_runtime.h>
#include <math.h>

#define NB   2
#define CIN  256
#define NN   6400
#define CKd  64
#define CVd  128
#define COd  256

using bf16   = __bf16;
using bf16x4 = __attribute__((ext_vector_type(4))) bf16;
using bf16x8 = __attribute__((ext_vector_type(8))) bf16;
using f32x4  = __attribute__((ext_vector_type(4))) float;

__device__ __forceinline__ void lds_cp16(const void* g, void* l) {
    __builtin_amdgcn_global_load_lds((const __attribute__((address_space(1))) void*)g,
                                     (__attribute__((address_space(3))) void*)l, 16, 0, 0);
}

// ---------------------------------------------------------------------------
// k/q/v projection, r16: prep_kernel FOLDED IN (one fewer dispatch + no
// weight round-trip).  Weights reg-staged as fp32, BN-scale applied during
// the bf16 pack, ds_write_b128 into the same XOR LDS layout the DMA used.
// Biases computed inline at the epilogue.  Split-K two-pass staging (r15,
// 32 KB LDS -> 4 blocks/CU).  q weights/bias pre-scaled by 0.125*log2(e)
// so attn softmax is p = exp2(s + c).  grid (100, 4, NB).
// ---------------------------------------------------------------------------
__launch_bounds__(256, 4)
__global__ void projkqv_kernel(const float* __restrict__ x, const float* __restrict__ y,
                               const float* __restrict__ fk_w, const float* __restrict__ fk_g,
                               const float* __restrict__ fk_b, const float* __restrict__ fk_m,
                               const float* __restrict__ fk_v,
                               const float* __restrict__ fq_w, const float* __restrict__ fq_g,
                               const float* __restrict__ fq_b, const float* __restrict__ fq_m,
                               const float* __restrict__ fq_v,
                               const float* __restrict__ fv_w, const float* __restrict__ fv_b,
                               bf16* __restrict__ kb, bf16* __restrict__ qb, bf16* __restrict__ vb)
{
    __shared__ __align__(16) bf16 sbuf[64 * 128];   // 16 KB src [n][c-half], XOR chunks
    __shared__ __align__(16) bf16 wbuf[64 * 128];   // 16 KB weights half, XOR chunks

    const int tid  = threadIdx.x;
    const int lane = tid & 63, wav = tid >> 6;
    const int l15  = lane & 15, quad = lane >> 4;
    const int b    = blockIdx.z, m = blockIdx.y;
    const int n0   = blockIdx.x * 64;
    const float QS = 0.18033688011112042f;   // 0.125 * log2(e)

    const float* srcg = ((m == 0) ? x : y) + (size_t)b * CIN * NN;

    const int key = l15 & 7;
    f32x4 acc[4];
#pragma unroll
    for (int j = 0; j < 4; ++j) acc[j] = (f32x4){0.f, 0.f, 0.f, 0.f};

    for (int p = 0; p < 2; ++p) {
        if (p) __syncthreads();            // all waves done reading pass-0 bufs

        // weights half: reg-stage fp32 + BN-fold + cvt -> XOR LDS layout
        {
            const int r4  = lane >> 4;
            const int c16 = lane & 15;
#pragma unroll
            for (int i = 0; i < 4; ++i) {
                const int r  = wav * 16 + i * 4 + r4;
                const int cs = c16 ^ (r & 7);
                const float* ws = (m == 0) ? (fk_w + (size_t)r * CIN)
                                : (m == 1) ? (fq_w + (size_t)r * CIN)
                                : (fv_w + (size_t)((m - 2) * 64 + r) * CIN);
                const float4 w0 = *(const float4*)(ws + p * 128 + cs * 8);
                const float4 w1 = *(const float4*)(ws + p * 128 + cs * 8 + 4);
                float a = 1.0f;
                if (m == 0)      a = fk_g[r] * rsqrtf(fk_v[r] + 1e-5f);
                else if (m == 1) a = fq_g[r] * rsqrtf(fq_v[r] + 1e-5f) * QS;
                bf16x8 pk;
                pk[0] = (bf16)(w0.x * a); pk[1] = (bf16)(w0.y * a);
                pk[2] = (bf16)(w0.z * a); pk[3] = (bf16)(w0.w * a);
                pk[4] = (bf16)(w1.x * a); pk[5] = (bf16)(w1.y * a);
                pk[6] = (bf16)(w1.z * a); pk[7] = (bf16)(w1.w * a);
                *(bf16x8*)&wbuf[r * 128 + c16 * 8] = pk;
            }
        }
        // src half: load + cvt + packed b128 scatter (register transpose)
        {
            const int nl = (tid & 15) * 4;
            const int cq = tid >> 4;            // 0..15 local chunk
            const int cb = p * 128 + cq * 8;
            float4 v[8];
#pragma unroll
            for (int e = 0; e < 8; ++e)
                v[e] = *(const float4*)(srcg + (size_t)(cb + e) * NN + n0 + nl);
#pragma unroll
            for (int i = 0; i < 4; ++i) {
                const int n = nl + i;
                bf16x8 pk;
#pragma unroll
                for (int e = 0; e < 8; ++e) pk[e] = (bf16)(&v[e].x)[i];
                *(bf16x8*)&sbuf[n * 128 + ((cq ^ (n & 7)) * 8)] = pk;
            }
        }
        __syncthreads();                   // drain ds_writes

        if (m < 2) {
            const int arow = wav * 16 + l15;
#pragma unroll
            for (int k4 = 0; k4 < 16; k4 += 4) {
                const bf16x8 af = *(const bf16x8*)&sbuf[arow * 128 + (((k4 + quad) ^ key) * 8)];
#pragma unroll
                for (int nt = 0; nt < 4; ++nt) {
                    const int brow = nt * 16 + l15;
                    const bf16x8 bfw = *(const bf16x8*)&wbuf[brow * 128 + (((k4 + quad) ^ key) * 8)];
                    acc[nt] = __builtin_amdgcn_mfma_f32_16x16x32_bf16(af, bfw, acc[nt], 0, 0, 0);
                }
            }
        } else {
            const int arow = wav * 16 + l15;
#pragma unroll
            for (int k4 = 0; k4 < 16; k4 += 4) {
                const bf16x8 af = *(const bf16x8*)&wbuf[arow * 128 + (((k4 + quad) ^ key) * 8)];
#pragma unroll
                for (int nt = 0; nt < 4; ++nt) {
                    const int brow = nt * 16 + l15;
                    const bf16x8 bfy = *(const bf16x8*)&sbuf[brow * 128 + (((k4 + quad) ^ key) * 8)];
                    acc[nt] = __builtin_amdgcn_mfma_f32_16x16x32_bf16(af, bfy, acc[nt], 0, 0, 0);
                }
            }
        }
    }

    if (m < 2) {
        bf16* dst = (m == 0) ? kb : qb;
        const int nb = n0 + wav * 16;
#pragma unroll
        for (int nt = 0; nt < 4; ++nt) {
            float bv;
            {
                const int c = nt * 16 + l15;
                if (m == 0) {
                    const float a = fk_g[c] * rsqrtf(fk_v[c] + 1e-5f);
                    bv = fk_b[c] - fk_m[c] * a;
                } else {
                    const float a = fq_g[c] * rsqrtf(fq_v[c] + 1e-5f);
                    bv = (fq_b[c] - fq_m[c] * a) * QS;
                }
            }
#pragma unroll
            for (int r = 0; r < 4; ++r) {
                const int n = nb + quad * 4 + r;
                dst[((size_t)b * NN + n) * CKd + nt * 16 + l15] = (bf16)(acc[nt][r] + bv);
            }
        }
    } else {
        const int cv0 = (m - 2) * 64 + wav * 16;
#pragma unroll
        for (int r = 0; r < 4; ++r) {
            const int cv = cv0 + quad * 4 + r;
            const float bv = fv_b[cv];
#pragma unroll
            for (int nt = 0; nt < 4; ++nt)
                vb[((size_t)b * CVd + cv) * NN + n0 + nt * 16 + l15] = (bf16)(acc[nt][r] + bv);
        }
    }
}

// ---------------------------------------------------------------------------
// Flash attention — EXACT r11/r13 kernel (proven 54.5-57.6 us band).
// r15's softmax<->PV interleave REGRESSED (54.6 -> 57.7): interleaved
// ds_writes inflate the lgkmcnt queue the PV ds_reads wait on (same class
// of hazard as r14).  Wave-level HW co-scheduling already overlaps the
// pipes (m114); keep the clean 2-phase structure.
// q=64/wave in two qt-pair phases; double-buffered K/V DMA, 1 barrier/iter;
// p = exp2(s + c) (q pre-scaled by log2e).  LDS 64 KB, (256,2), no spill.
// grid 25*NB*KS (KS=10 -> 500 blocks, one balanced round).
// ---------------------------------------------------------------------------
__launch_bounds__(256, 2)
__global__ void attn_kernel(const bf16* __restrict__ qb, const bf16* __restrict__ kb,
                            const bf16* __restrict__ vb,
                            bf16* __restrict__ pO, float* __restrict__ pl, int KS)
{
    __shared__ __align__(16) bf16 kbuf[2][64 * 64];        // 16 KB
    __shared__ __align__(16) bf16 vbuf[2][128 * 64];       // 32 KB
    __shared__ __align__(16) bf16 p_lds[4][2][16][64];     // 16 KB per-wave/qt-pair

    const int lane = threadIdx.x & 63;
    const int wav  = threadIdx.x >> 6;
    const int l15  = lane & 15;
    const int quad = lane >> 4;
    const int r8   = lane >> 3;
    const int c_src = (lane & 7) ^ r8;
    const int sw   = l15 & 7;
    const int pkey = (l15 & 7) << 1;

    const int id    = blockIdx.x;
    const int ks    = id % KS;
    const int rst   = id / KS;
    const int b     = rst & 1;
    const int qtile = rst >> 1;
    const int q0    = qtile * 256 + wav * 64;

    const bf16* qrow = qb + (size_t)b * NN * CKd;
    const bf16* krow = kb + (size_t)b * NN * CKd;
    const bf16* vrow = vb + (size_t)b * CVd * NN;

    bf16x8 qf[4][2];
#pragma unroll
    for (int qt = 0; qt < 4; ++qt)
#pragma unroll
        for (int s = 0; s < 2; ++s)
            qf[qt][s] = *(const bf16x8*)(qrow + (size_t)(q0 + qt * 16 + l15) * CKd + s * 32 + quad * 8);

    f32x4 acc[4][8];
#pragma unroll
    for (int qt = 0; qt < 4; ++qt)
#pragma unroll
        for (int cv = 0; cv < 8; ++cv) acc[qt][cv] = (f32x4){0.f, 0.f, 0.f, 0.f};
    float psum[4] = {0.f, 0.f, 0.f, 0.f};

    const int t0 = (100 * ks) / KS;
    const int nt = (100 * (ks + 1)) / KS - t0;

    auto stage = [&](int t, int bi) {
        const int key0 = t * 64;
        lds_cp16(krow + (size_t)(key0 + wav * 8 + r8) * CKd + c_src * 8,
                 &kbuf[bi][(wav * 8) * 64]);
        lds_cp16(krow + (size_t)(key0 + (wav + 4) * 8 + r8) * CKd + c_src * 8,
                 &kbuf[bi][((wav + 4) * 8) * 64]);
#pragma unroll
        for (int g4 = 0; g4 < 4; ++g4) {
            const int g = wav * 4 + g4;
            lds_cp16(vrow + (size_t)(g * 8 + r8) * NN + key0 + c_src * 8,
                     &vbuf[bi][(g * 8) * 64]);
        }
    };

    stage(t0, 0);   // prologue

    for (int t = 0; t < nt; ++t) {
        __syncthreads();                    // drains DMA(t); guards buf reuse
        if (t + 1 < nt) stage(t0 + t + 1, (t + 1) & 1);
        const bf16* kcur = &kbuf[t & 1][0];
        const bf16* vcur = &vbuf[t & 1][0];

#pragma unroll
        for (int ph = 0; ph < 2; ++ph) {
            // ---- S^T = K * Q^T for this qt-pair ----
            f32x4 s4[2][4];
#pragma unroll
            for (int kt = 0; kt < 4; ++kt) {
                const int rr = kt * 16 + l15;
                const bf16x8 kf0 = *(const bf16x8*)&kcur[rr * 64 + ((quad ^ sw) * 8)];
                const bf16x8 kf1 = *(const bf16x8*)&kcur[rr * 64 + (((4 + quad) ^ sw) * 8)];
#pragma unroll
                for (int qtl = 0; qtl < 2; ++qtl) {
                    const int qt = ph * 2 + qtl;
                    f32x4 z = (f32x4){0.f, 0.f, 0.f, 0.f};
                    z = __builtin_amdgcn_mfma_f32_16x16x32_bf16(kf0, qf[qt][0], z, 0, 0, 0);
                    z = __builtin_amdgcn_mfma_f32_16x16x32_bf16(kf1, qf[qt][1], z, 0, 0, 0);
                    s4[qtl][kt] = z;
                }
            }

            // ---- p = exp2(s + c) [q pre-scaled by log2e], pack to LDS ----
#pragma unroll
            for (int qtl = 0; qtl < 2; ++qtl) {
                float ps = 0.f;
#pragma unroll
                for (int kt = 0; kt < 4; ++kt) {
                    bf16x4 pk;
#pragma unroll
                    for (int r = 0; r < 4; ++r) {
                        const float p = exp2f(s4[qtl][kt][r] - 11.541560327111707f);
                        ps += p;
                        pk[r] = (bf16)p;
                    }
                    *(bf16x4*)&p_lds[wav][qtl][l15][((kt * 4 + quad) ^ pkey) * 4] = pk;
                }
                psum[ph * 2 + qtl] += ps;
            }

            // ---- ctx^T += V^T * P^T for this qt-pair ----
#pragma unroll
            for (int sp = 0; sp < 2; ++sp) {
                const bf16x8 pf0 = *(const bf16x8*)&p_lds[wav][0][l15][((sp * 8 + quad * 2) ^ pkey) * 4];
                const bf16x8 pf1 = *(const bf16x8*)&p_lds[wav][1][l15][((sp * 8 + quad * 2) ^ pkey) * 4];
#pragma unroll
                for (int cvt = 0; cvt < 8; ++cvt) {
                    const int rr = cvt * 16 + l15;
                    const bf16x8 vf = *(const bf16x8*)&vcur[rr * 64 + (((sp * 4 + quad) ^ sw) * 8)];
                    acc[ph * 2 + 0][cvt] = __builtin_amdgcn_mfma_f32_16x16x32_bf16(vf, pf0, acc[ph * 2 + 0][cvt], 0, 0, 0);
                    acc[ph * 2 + 1][cvt] = __builtin_amdgcn_mfma_f32_16x16x32_bf16(vf, pf1, acc[ph * 2 + 1][cvt], 0, 0, 0);
                }
            }
        }
    }

    // ---- epilogue: transpose acc through LDS -> coalesced pO stores ----
    __syncthreads();
    bf16* tbuf = &p_lds[wav][0][0][0];   // per-wave 2048 bf16 = [16 rows][128]
    const size_t pb = (size_t)ks * NB + b;
#pragma unroll
    for (int qt = 0; qt < 4; ++qt) {
        psum[qt] += __shfl_xor(psum[qt], 16);
        psum[qt] += __shfl_xor(psum[qt], 32);
#pragma unroll
        for (int cvt = 0; cvt < 8; ++cvt) {
            bf16x4 pk;
#pragma unroll
            for (int r = 0; r < 4; ++r) pk[r] = (bf16)acc[qt][cvt][r];
            const int u = (cvt * 4 + quad) ^ (l15 << 1);
            *(bf16x4*)&tbuf[l15 * 128 + u * 4] = pk;
        }
#pragma unroll
        for (int j = 0; j < 4; ++j) {
            const int row = j * 4 + (lane >> 4);
            const int g   = ((lane & 15) * 2) ^ ((row & 15) << 1);
            const bf16x8 vv = *(const bf16x8*)&tbuf[row * 128 + g * 4];
            *(bf16x8*)(pO + (pb * NN + q0 + qt * 16) * CVd + j * 512 + lane * 8) = vv;
        }
        if (quad == 0) pl[pb * NN + q0 + qt * 16 + l15] = psum[qt];
    }
}

// ---------------------------------------------------------------------------
// Fused combine + output projection, r16: prep fold — W_w reg-staged as
// fp32 + cvt (same XOR layout), W_b read direct.  Keeps r15's phase-1
// prefetch and two 128-co passes (40 KB LDS -> 4 blocks/CU).
// out = gamma*(W.ctx + W_b) + x.  grid (200, NB).
// ---------------------------------------------------------------------------
__launch_bounds__(256, 4)
__global__ void outproj_kernel(const bf16* __restrict__ pO, const float* __restrict__ pl,
                               const float* __restrict__ W_w, const float* __restrict__ W_b,
                               const float* __restrict__ x, const float* __restrict__ gam,
                               float* __restrict__ out, int KS)
{
    __shared__ __align__(16) bf16 wbuf[128 * 128];   // 32 KB (co half)
    __shared__ __align__(16) bf16 cbuf[32 * 128];    // 8 KB

    const int tid  = threadIdx.x;
    const int lane = tid & 63, wav = tid >> 6;
    const int l15  = lane & 15, quad = lane >> 4;
    const int b    = blockIdx.y;
    const int n0   = blockIdx.x * 32;

    auto stage_w = [&](int p) {
        const int r4 = lane >> 4;
        const int c16 = lane & 15;
#pragma unroll
        for (int i = 0; i < 8; ++i) {
            const int r  = wav * 32 + i * 4 + r4;
            const int cs = c16 ^ (r & 7);
            const float* ws = W_w + (size_t)(p * 128 + r) * CVd + cs * 8;
            const float4 w0 = *(const float4*)(ws);
            const float4 w1 = *(const float4*)(ws + 4);
            bf16x8 pk;
            pk[0] = (bf16)w0.x; pk[1] = (bf16)w0.y; pk[2] = (bf16)w0.z; pk[3] = (bf16)w0.w;
            pk[4] = (bf16)w1.x; pk[5] = (bf16)w1.y; pk[6] = (bf16)w1.z; pk[7] = (bf16)w1.w;
            *(bf16x8*)&wbuf[r * 128 + c16 * 8] = pk;
        }
    };
    stage_w(0);

    // ---- phase 1: accumulate KS chunks of pO, 16 vals/thread, prefetched ----
    const int tn = tid >> 3;
    const int tc = (tid & 7) * 16;
    const size_t kstr = (size_t)NB * NN * CVd;
    const bf16* src0 = pO + ((size_t)b * NN + n0 + tn) * CVd + tc;
    float vacc[16];
#pragma unroll
    for (int i = 0; i < 16; ++i) vacc[i] = 0.f;
    float L = 0.f;

    bf16x8 c0 = *(const bf16x8*)(src0);
    bf16x8 c1 = *(const bf16x8*)(src0 + 8);
    for (int ksi = 0; ksi < KS; ++ksi) {
        bf16x8 nx0 = c0, nx1 = c1;
        if (ksi + 1 < KS) {
            const bf16* s = src0 + (size_t)(ksi + 1) * kstr;
            nx0 = *(const bf16x8*)(s);
            nx1 = *(const bf16x8*)(s + 8);
        }
        L += pl[(size_t)(ksi * NB + b) * NN + n0 + tn];
#pragma unroll
        for (int e = 0; e < 8; ++e) vacc[e]     += (float)c0[e];
#pragma unroll
        for (int e = 0; e < 8; ++e) vacc[8 + e] += (float)c1[e];
        c0 = nx0; c1 = nx1;
    }
    {
        const float rL = 1.0f / L;
#pragma unroll
        for (int j = 0; j < 2; ++j) {
            bf16x8 o;
#pragma unroll
            for (int e = 0; e < 8; ++e) o[e] = (bf16)(vacc[j * 8 + e] * rL);
            const int c = (tid & 7) * 2 + j;
            *(bf16x8*)&cbuf[tn * 128 + ((c ^ (tn & 7)) * 8)] = o;
        }
    }
    __syncthreads();   // drains wbuf half-0 + cbuf ds_writes

    const float gm = gam[0];

    auto mfma_pass = [&](f32x4 (&acc)[2][2]) {
#pragma unroll
        for (int i = 0; i < 2; ++i)
#pragma unroll
            for (int j = 0; j < 2; ++j) acc[i][j] = (f32x4){0.f, 0.f, 0.f, 0.f};
#pragma unroll
        for (int kk = 0; kk < 4; ++kk) {
#pragma unroll
            for (int cot = 0; cot < 2; ++cot) {
                const int arow = wav * 32 + cot * 16 + l15;
                const bf16x8 af = *(const bf16x8*)&wbuf[arow * 128 + (((kk * 4 + quad) ^ (arow & 7)) * 8)];
#pragma unroll
                for (int nt = 0; nt < 2; ++nt) {
                    const int brow = nt * 16 + l15;
                    const bf16x8 bfc = *(const bf16x8*)&cbuf[brow * 128 + (((kk * 4 + quad) ^ (brow & 7)) * 8)];
                    acc[cot][nt] = __builtin_amdgcn_mfma_f32_16x16x32_bf16(af, bfc, acc[cot][nt], 0, 0, 0);
                }
            }
        }
    };
    auto store_pass = [&](const f32x4 (&acc)[2][2], int p) {
#pragma unroll
        for (int cot = 0; cot < 2; ++cot)
#pragma unroll
            for (int r = 0; r < 4; ++r) {
                const int co = p * 128 + wav * 32 + cot * 16 + quad * 4 + r;
                const float bv = W_b[co];
#pragma unroll
                for (int nt = 0; nt < 2; ++nt) {
                    const int n = n0 + nt * 16 + l15;
                    const size_t a = ((size_t)b * COd + co) * NN + n;
                    out[a] = gm * (acc[cot][nt][r] + bv) + x[a];
                }
            }
    };

    f32x4 acc0[2][2];
    mfma_pass(acc0);
    __syncthreads();          // all waves done reading wbuf half 0
    stage_w(1);               // issue half-1 writes ...
    store_pass(acc0, 0);      // ... overlapped with half-0 stores
    __syncthreads();          // drain half-1 ds_writes
    f32x4 acc1[2][2];
    mfma_pass(acc1);
    store_pass(acc1, 1);
}

// ---------------------------------------------------------------------------
extern "C" void kernel_launch(void* const* d_in, const int* in_sizes, int n_in,
                              void* d_out, int out_size, void* d_ws, size_t ws_size,
                              hipStream_t stream)
{
    const float* x     = (const float*)d_in[0];
    const float* y     = (const float*)d_in[1];
    const float* fk_w  = (const float*)d_in[2];
    const float* fk_g  = (const float*)d_in[3];
    const float* fk_b  = (const float*)d_in[4];
    const float* fk_m  = (const float*)d_in[5];
    const float* fk_v  = (const float*)d_in[6];
    const float* fq_w  = (const float*)d_in[7];
    const float* fq_g  = (const float*)d_in[8];
    const float* fq_b  = (const float*)d_in[9];
    const float* fq_m  = (const float*)d_in[10];
    const float* fq_v  = (const float*)d_in[11];
    const float* fv_w  = (const float*)d_in[12];
    const float* fv_b  = (const float*)d_in[13];
    const float* W_w   = (const float*)d_in[14];
    const float* W_b   = (const float*)d_in[15];
    const float* gamma = (const float*)d_in[16];
    float* out = (float*)d_out;

    char* ws = (char*)d_ws;
    size_t off = 0;
    auto carve = [&](size_t bytes) -> char* {
        char* p = ws + off;
        off = (off + bytes + 255) & ~(size_t)255;
        return p;
    };

    bf16*  kb   = (bf16*)carve((size_t)NB * NN * CKd * 2);
    bf16*  qbuf = (bf16*)carve((size_t)NB * NN * CKd * 2);
    bf16*  vb   = (bf16*)carve((size_t)NB * CVd * NN * 2);

    const size_t region = ws_size - off;
    const size_t per_ks = (size_t)NB * NN * CVd * 2 + (size_t)NB * NN * 4 + 512;
    int KS = 1;
    {
        const int cand[6] = {10, 8, 5, 4, 2, 1};
        for (int i = 0; i < 6; ++i)
            if ((size_t)cand[i] * per_ks <= region) { KS = cand[i]; break; }
    }
    bf16*  pO = (bf16*)carve((size_t)KS * NB * NN * CVd * 2);
    float* pl = (float*)carve((size_t)KS * NB * NN * 4);

    const dim3 blk(256);
    projkqv_kernel<<<dim3(100, 4, NB), blk, 0, stream>>>(x, y,
                                                         fk_w, fk_g, fk_b, fk_m, fk_v,
                                                         fq_w, fq_g, fq_b, fq_m, fq_v,
                                                         fv_w, fv_b, kb, qbuf, vb);
    attn_kernel<<<dim3(25 * NB * KS), blk, 0, stream>>>(qbuf, kb, vb, pO, pl, KS);
    outproj_kernel<<<dim3(200, NB), blk, 0, stream>>>(pO, pl, W_w, W_b, x, gamma, out, KS);
}

// Round 3
// 167.851 us; speedup vs baseline: 1.0302x; 1.0185x over previous
//
#include <hip/hip_runtime.h>
#include <math.h>

#define NB   2
#define CIN  256
#define NN   6400
#define CKd  64
#define CVd  128
#define COd  256

using bf16   = __bf16;
using bf16x4 = __attribute__((ext_vector_type(4))) bf16;
using bf16x8 = __attribute__((ext_vector_type(8))) bf16;
using f32x4  = __attribute__((ext_vector_type(4))) float;

__device__ __forceinline__ void lds_cp16(const void* g, void* l) {
    __builtin_amdgcn_global_load_lds((const __attribute__((address_space(1))) void*)g,
                                     (__attribute__((address_space(3))) void*)l, 16, 0, 0);
}

// ---------------------------------------------------------------------------
// k/q/v projection (r16, proven): prep folded in; weights reg-staged fp32,
// BN-scale applied during bf16 pack; split-K two-pass staging, 32 KB LDS,
// 4 blocks/CU.  q weights/bias pre-scaled by 0.125*log2(e) so attn softmax
// is p = exp2(s + c).  grid (100, 4, NB).
// ---------------------------------------------------------------------------
__launch_bounds__(256, 4)
__global__ void projkqv_kernel(const float* __restrict__ x, const float* __restrict__ y,
                               const float* __restrict__ fk_w, const float* __restrict__ fk_g,
                               const float* __restrict__ fk_b, const float* __restrict__ fk_m,
                               const float* __restrict__ fk_v,
                               const float* __restrict__ fq_w, const float* __restrict__ fq_g,
                               const float* __restrict__ fq_b, const float* __restrict__ fq_m,
                               const float* __restrict__ fq_v,
                               const float* __restrict__ fv_w, const float* __restrict__ fv_b,
                               bf16* __restrict__ kb, bf16* __restrict__ qb, bf16* __restrict__ vb)
{
    __shared__ __align__(16) bf16 sbuf[64 * 128];   // 16 KB src [n][c-half], XOR chunks
    __shared__ __align__(16) bf16 wbuf[64 * 128];   // 16 KB weights half, XOR chunks

    const int tid  = threadIdx.x;
    const int lane = tid & 63, wav = tid >> 6;
    const int l15  = lane & 15, quad = lane >> 4;
    const int b    = blockIdx.z, m = blockIdx.y;
    const int n0   = blockIdx.x * 64;
    const float QS = 0.18033688011112042f;   // 0.125 * log2(e)

    const float* srcg = ((m == 0) ? x : y) + (size_t)b * CIN * NN;

    const int key = l15 & 7;
    f32x4 acc[4];
#pragma unroll
    for (int j = 0; j < 4; ++j) acc[j] = (f32x4){0.f, 0.f, 0.f, 0.f};

    for (int p = 0; p < 2; ++p) {
        if (p) __syncthreads();            // all waves done reading pass-0 bufs

        // weights half: reg-stage fp32 + BN-fold + cvt -> XOR LDS layout
        {
            const int r4  = lane >> 4;
            const int c16 = lane & 15;
#pragma unroll
            for (int i = 0; i < 4; ++i) {
                const int r  = wav * 16 + i * 4 + r4;
                const int cs = c16 ^ (r & 7);
                const float* ws = (m == 0) ? (fk_w + (size_t)r * CIN)
                                : (m == 1) ? (fq_w + (size_t)r * CIN)
                                : (fv_w + (size_t)((m - 2) * 64 + r) * CIN);
                const float4 w0 = *(const float4*)(ws + p * 128 + cs * 8);
                const float4 w1 = *(const float4*)(ws + p * 128 + cs * 8 + 4);
                float a = 1.0f;
                if (m == 0)      a = fk_g[r] * rsqrtf(fk_v[r] + 1e-5f);
                else if (m == 1) a = fq_g[r] * rsqrtf(fq_v[r] + 1e-5f) * QS;
                bf16x8 pk;
                pk[0] = (bf16)(w0.x * a); pk[1] = (bf16)(w0.y * a);
                pk[2] = (bf16)(w0.z * a); pk[3] = (bf16)(w0.w * a);
                pk[4] = (bf16)(w1.x * a); pk[5] = (bf16)(w1.y * a);
                pk[6] = (bf16)(w1.z * a); pk[7] = (bf16)(w1.w * a);
                *(bf16x8*)&wbuf[r * 128 + c16 * 8] = pk;
            }
        }
        // src half: load + cvt + packed b128 scatter (register transpose)
        {
            const int nl = (tid & 15) * 4;
            const int cq = tid >> 4;            // 0..15 local chunk
            const int cb = p * 128 + cq * 8;
            float4 v[8];
#pragma unroll
            for (int e = 0; e < 8; ++e)
                v[e] = *(const float4*)(srcg + (size_t)(cb + e) * NN + n0 + nl);
#pragma unroll
            for (int i = 0; i < 4; ++i) {
                const int n = nl + i;
                bf16x8 pk;
#pragma unroll
                for (int e = 0; e < 8; ++e) pk[e] = (bf16)(&v[e].x)[i];
                *(bf16x8*)&sbuf[n * 128 + ((cq ^ (n & 7)) * 8)] = pk;
            }
        }
        __syncthreads();                   // drain ds_writes

        if (m < 2) {
            const int arow = wav * 16 + l15;
#pragma unroll
            for (int k4 = 0; k4 < 16; k4 += 4) {
                const bf16x8 af = *(const bf16x8*)&sbuf[arow * 128 + (((k4 + quad) ^ key) * 8)];
#pragma unroll
                for (int nt = 0; nt < 4; ++nt) {
                    const int brow = nt * 16 + l15;
                    const bf16x8 bfw = *(const bf16x8*)&wbuf[brow * 128 + (((k4 + quad) ^ key) * 8)];
                    acc[nt] = __builtin_amdgcn_mfma_f32_16x16x32_bf16(af, bfw, acc[nt], 0, 0, 0);
                }
            }
        } else {
            const int arow = wav * 16 + l15;
#pragma unroll
            for (int k4 = 0; k4 < 16; k4 += 4) {
                const bf16x8 af = *(const bf16x8*)&wbuf[arow * 128 + (((k4 + quad) ^ key) * 8)];
#pragma unroll
                for (int nt = 0; nt < 4; ++nt) {
                    const int brow = nt * 16 + l15;
                    const bf16x8 bfy = *(const bf16x8*)&sbuf[brow * 128 + (((k4 + quad) ^ key) * 8)];
                    acc[nt] = __builtin_amdgcn_mfma_f32_16x16x32_bf16(af, bfy, acc[nt], 0, 0, 0);
                }
            }
        }
    }

    if (m < 2) {
        bf16* dst = (m == 0) ? kb : qb;
        const int nb = n0 + wav * 16;
#pragma unroll
        for (int nt = 0; nt < 4; ++nt) {
            float bv;
            {
                const int c = nt * 16 + l15;
                if (m == 0) {
                    const float a = fk_g[c] * rsqrtf(fk_v[c] + 1e-5f);
                    bv = fk_b[c] - fk_m[c] * a;
                } else {
                    const float a = fq_g[c] * rsqrtf(fq_v[c] + 1e-5f);
                    bv = (fq_b[c] - fq_m[c] * a) * QS;
                }
            }
#pragma unroll
            for (int r = 0; r < 4; ++r) {
                const int n = nb + quad * 4 + r;
                dst[((size_t)b * NN + n) * CKd + nt * 16 + l15] = (bf16)(acc[nt][r] + bv);
            }
        }
    } else {
        const int cv0 = (m - 2) * 64 + wav * 16;
#pragma unroll
        for (int r = 0; r < 4; ++r) {
            const int cv = cv0 + quad * 4 + r;
            const float bv = fv_b[cv];
#pragma unroll
            for (int nt = 0; nt < 4; ++nt)
                vb[((size_t)b * CVd + cv) * NN + n0 + nt * 16 + l15] = (bf16)(acc[nt][r] + bv);
        }
    }
}

// ---------------------------------------------------------------------------
// Flash attention r17: OCCUPANCY restructure (counters: Mfma 21 + VALU 42 =
// 63% issue, 37% idle at 2 waves/SIMD -> need more waves, NOT intra-wave
// interleave which failed r14/r15).
//   - block = 64 q rows (16 q/wave): acc[8] = 32 VGPR (was 128), p_lds 8 KB.
//   - V single-buffered + counted-vmcnt mid-barrier: stageV issued post-PV,
//     drained by "s_waitcnt vmcnt(2)" (leaves K prefetch in flight) before
//     PV of the next iter -> V latency hides under QK+softmax.
//   - K stays double-buffered (prefetch gets a full iteration of cover).
//   - LDS 40 KB -> 4 blocks/CU = 4 waves/SIMD (was 2).
//   - grid 100*NB*KS, KS=5 -> 1000 blocks ~ one full round at 4/CU; pO
//     traffic halves (16.4 MB).
// Data-path code (XOR swizzles, DMA lane maps, epilogue transpose) is the
// proven r13 code with the qt/ph dimensions dropped.
// ---------------------------------------------------------------------------
__launch_bounds__(256, 4)
__global__ void attn_kernel(const bf16* __restrict__ qb, const bf16* __restrict__ kb,
                            const bf16* __restrict__ vb,
                            bf16* __restrict__ pO, float* __restrict__ pl, int KS)
{
    __shared__ __align__(16) bf16 kbuf[2][64 * 64];   // 16 KB  K double-buffer
    __shared__ __align__(16) bf16 vbuf[128 * 64];     // 16 KB  V single buffer
    __shared__ __align__(16) bf16 p_lds[4][16][64];   // 8 KB   per-wave P

    const int lane = threadIdx.x & 63;
    const int wav  = threadIdx.x >> 6;
    const int l15  = lane & 15;
    const int quad = lane >> 4;
    const int r8   = lane >> 3;
    const int c_src = (lane & 7) ^ r8;
    const int sw   = l15 & 7;
    const int pkey = (l15 & 7) << 1;

    const int id    = blockIdx.x;
    const int ks    = id % KS;
    const int rst   = id / KS;
    const int b     = rst & 1;
    const int qtile = rst >> 1;          // 0..99
    const int q0    = qtile * 64 + wav * 16;

    const bf16* qrow = qb + (size_t)b * NN * CKd;
    const bf16* krow = kb + (size_t)b * NN * CKd;
    const bf16* vrow = vb + (size_t)b * CVd * NN;

    bf16x8 qf[2];
#pragma unroll
    for (int s = 0; s < 2; ++s)
        qf[s] = *(const bf16x8*)(qrow + (size_t)(q0 + l15) * CKd + s * 32 + quad * 8);

    const float ZC = -11.541560327111707f;
    const f32x4 zini = (f32x4){ZC, ZC, ZC, ZC};

    f32x4 acc[8];
#pragma unroll
    for (int cv = 0; cv < 8; ++cv) acc[cv] = (f32x4){0.f, 0.f, 0.f, 0.f};
    float psum = 0.f;

    const int t0 = (100 * ks) / KS;
    const int nt = (100 * (ks + 1)) / KS - t0;

    auto stageK = [&](int t, int bi) {
        const int key0 = t * 64;
        lds_cp16(krow + (size_t)(key0 + wav * 8 + r8) * CKd + c_src * 8,
                 &kbuf[bi][(wav * 8) * 64]);
        lds_cp16(krow + (size_t)(key0 + (wav + 4) * 8 + r8) * CKd + c_src * 8,
                 &kbuf[bi][((wav + 4) * 8) * 64]);
    };
    auto stageV = [&](int t) {
        const int key0 = t * 64;
#pragma unroll
        for (int g4 = 0; g4 < 4; ++g4) {
            const int g = wav * 4 + g4;
            lds_cp16(vrow + (size_t)(g * 8 + r8) * NN + key0 + c_src * 8,
                     &vbuf[(g * 8) * 64]);
        }
    };

    stageK(t0, 0);
    stageV(t0);
    __syncthreads();     // drain prologue DMA

    for (int t = 0; t < nt; ++t) {
        if (t + 1 < nt) stageK(t0 + t + 1, (t + 1) & 1);   // K prefetch, full-iter cover
        const bf16* kcur = &kbuf[t & 1][0];

        // ---- S^T = K * Q^T, C-init = softmax constant ----
        f32x4 s4[4];
#pragma unroll
        for (int kt = 0; kt < 4; ++kt) {
            const int rr = kt * 16 + l15;
            const bf16x8 kf0 = *(const bf16x8*)&kcur[rr * 64 + ((quad ^ sw) * 8)];
            const bf16x8 kf1 = *(const bf16x8*)&kcur[rr * 64 + (((4 + quad) ^ sw) * 8)];
            f32x4 z = zini;
            z = __builtin_amdgcn_mfma_f32_16x16x32_bf16(kf0, qf[0], z, 0, 0, 0);
            z = __builtin_amdgcn_mfma_f32_16x16x32_bf16(kf1, qf[1], z, 0, 0, 0);
            s4[kt] = z;
        }

        // ---- p = exp2(s + c), pack to wave-private p_lds ----
#pragma unroll
        for (int kt = 0; kt < 4; ++kt) {
            bf16x4 pk;
#pragma unroll
            for (int r = 0; r < 4; ++r) {
                const float p = exp2f(s4[kt][r]);
                psum += p;
                pk[r] = (bf16)p;
            }
            *(bf16x4*)&p_lds[wav][l15][((kt * 4 + quad) ^ pkey) * 4] = pk;
        }

        // ---- V(t) ready?  counted wait: leave the 2 K-prefetch DMAs in flight
        if (t + 1 < nt) { asm volatile("s_waitcnt vmcnt(2)" ::: "memory"); }
        else            { asm volatile("s_waitcnt vmcnt(0)" ::: "memory"); }
        __builtin_amdgcn_s_barrier();

        // ---- ctx^T += V^T * P^T ----
#pragma unroll
        for (int sp = 0; sp < 2; ++sp) {
            const bf16x8 pf = *(const bf16x8*)&p_lds[wav][l15][((sp * 8 + quad * 2) ^ pkey) * 4];
#pragma unroll
            for (int cvt = 0; cvt < 8; ++cvt) {
                const int rr = cvt * 16 + l15;
                const bf16x8 vf = *(const bf16x8*)&vbuf[rr * 64 + (((sp * 4 + quad) ^ sw) * 8)];
                acc[cvt] = __builtin_amdgcn_mfma_f32_16x16x32_bf16(vf, pf, acc[cvt], 0, 0, 0);
            }
        }

        __syncthreads();                    // all waves done reading vbuf (drains K prefetch too)
        if (t + 1 < nt) stageV(t0 + t + 1); // V stage: hides under next QK+softmax
    }

    // ---- epilogue: transpose acc through LDS (vbuf reused) -> coalesced pO ----
    psum += __shfl_xor(psum, 16);
    psum += __shfl_xor(psum, 32);
    bf16* tbuf = &vbuf[wav * 2048];      // per-wave [16 rows][128]
    const size_t pb = (size_t)ks * NB + b;
#pragma unroll
    for (int cvt = 0; cvt < 8; ++cvt) {
        bf16x4 pk;
#pragma unroll
        for (int r = 0; r < 4; ++r) pk[r] = (bf16)acc[cvt][r];
        const int u = (cvt * 4 + quad) ^ (l15 << 1);
        *(bf16x4*)&tbuf[l15 * 128 + u * 4] = pk;
    }
#pragma unroll
    for (int j = 0; j < 4; ++j) {
        const int row = j * 4 + (lane >> 4);
        const int g   = ((lane & 15) * 2) ^ ((row & 15) << 1);
        const bf16x8 vv = *(const bf16x8*)&tbuf[row * 128 + g * 4];
        *(bf16x8*)(pO + (pb * NN + q0 - wav * 16 + wav * 16) * CVd + j * 512 + lane * 8) = vv;
    }
    if (quad == 0) pl[pb * NN + q0 + l15] = psum;
}

// ---------------------------------------------------------------------------
// Fused combine + output projection (r16, proven): W_w reg-staged fp32+cvt,
// phase-1 KS-chunk accumulation with 1-deep prefetch, two 128-co passes,
// 40 KB LDS -> 4 blocks/CU.  out = gamma*(W.ctx + W_b) + x.  grid (200, NB).
// KS=5 now -> phase-1 reads halve.
// ---------------------------------------------------------------------------
__launch_bounds__(256, 4)
__global__ void outproj_kernel(const bf16* __restrict__ pO, const float* __restrict__ pl,
                               const float* __restrict__ W_w, const float* __restrict__ W_b,
                               const float* __restrict__ x, const float* __restrict__ gam,
                               float* __restrict__ out, int KS)
{
    __shared__ __align__(16) bf16 wbuf[128 * 128];   // 32 KB (co half)
    __shared__ __align__(16) bf16 cbuf[32 * 128];    // 8 KB

    const int tid  = threadIdx.x;
    const int lane = tid & 63, wav = tid >> 6;
    const int l15  = lane & 15, quad = lane >> 4;
    const int b    = blockIdx.y;
    const int n0   = blockIdx.x * 32;

    auto stage_w = [&](int p) {
        const int r4 = lane >> 4;
        const int c16 = lane & 15;
#pragma unroll
        for (int i = 0; i < 8; ++i) {
            const int r  = wav * 32 + i * 4 + r4;
            const int cs = c16 ^ (r & 7);
            const float* ws = W_w + (size_t)(p * 128 + r) * CVd + cs * 8;
            const float4 w0 = *(const float4*)(ws);
            const float4 w1 = *(const float4*)(ws + 4);
            bf16x8 pk;
            pk[0] = (bf16)w0.x; pk[1] = (bf16)w0.y; pk[2] = (bf16)w0.z; pk[3] = (bf16)w0.w;
            pk[4] = (bf16)w1.x; pk[5] = (bf16)w1.y; pk[6] = (bf16)w1.z; pk[7] = (bf16)w1.w;
            *(bf16x8*)&wbuf[r * 128 + c16 * 8] = pk;
        }
    };
    stage_w(0);

    // ---- phase 1: accumulate KS chunks of pO, 16 vals/thread, prefetched ----
    const int tn = tid >> 3;
    const int tc = (tid & 7) * 16;
    const size_t kstr = (size_t)NB * NN * CVd;
    const bf16* src0 = pO + ((size_t)b * NN + n0 + tn) * CVd + tc;
    float vacc[16];
#pragma unroll
    for (int i = 0; i < 16; ++i) vacc[i] = 0.f;
    float L = 0.f;

    bf16x8 c0 = *(const bf16x8*)(src0);
    bf16x8 c1 = *(const bf16x8*)(src0 + 8);
    for (int ksi = 0; ksi < KS; ++ksi) {
        bf16x8 nx0 = c0, nx1 = c1;
        if (ksi + 1 < KS) {
            const bf16* s = src0 + (size_t)(ksi + 1) * kstr;
            nx0 = *(const bf16x8*)(s);
            nx1 = *(const bf16x8*)(s + 8);
        }
        L += pl[(size_t)(ksi * NB + b) * NN + n0 + tn];
#pragma unroll
        for (int e = 0; e < 8; ++e) vacc[e]     += (float)c0[e];
#pragma unroll
        for (int e = 0; e < 8; ++e) vacc[8 + e] += (float)c1[e];
        c0 = nx0; c1 = nx1;
    }
    {
        const float rL = 1.0f / L;
#pragma unroll
        for (int j = 0; j < 2; ++j) {
            bf16x8 o;
#pragma unroll
            for (int e = 0; e < 8; ++e) o[e] = (bf16)(vacc[j * 8 + e] * rL);
            const int c = (tid & 7) * 2 + j;
            *(bf16x8*)&cbuf[tn * 128 + ((c ^ (tn & 7)) * 8)] = o;
        }
    }
    __syncthreads();   // drains wbuf half-0 + cbuf ds_writes

    const float gm = gam[0];

    auto mfma_pass = [&](f32x4 (&acc)[2][2]) {
#pragma unroll
        for (int i = 0; i < 2; ++i)
#pragma unroll
            for (int j = 0; j < 2; ++j) acc[i][j] = (f32x4){0.f, 0.f, 0.f, 0.f};
#pragma unroll
        for (int kk = 0; kk < 4; ++kk) {
#pragma unroll
            for (int cot = 0; cot < 2; ++cot) {
                const int arow = wav * 32 + cot * 16 + l15;
                const bf16x8 af = *(const bf16x8*)&wbuf[arow * 128 + (((kk * 4 + quad) ^ (arow & 7)) * 8)];
#pragma unroll
                for (int nt = 0; nt < 2; ++nt) {
                    const int brow = nt * 16 + l15;
                    const bf16x8 bfc = *(const bf16x8*)&cbuf[brow * 128 + (((kk * 4 + quad) ^ (brow & 7)) * 8)];
                    acc[cot][nt] = __builtin_amdgcn_mfma_f32_16x16x32_bf16(af, bfc, acc[cot][nt], 0, 0, 0);
                }
            }
        }
    };
    auto store_pass = [&](const f32x4 (&acc)[2][2], int p) {
#pragma unroll
        for (int cot = 0; cot < 2; ++cot)
#pragma unroll
            for (int r = 0; r < 4; ++r) {
                const int co = p * 128 + wav * 32 + cot * 16 + quad * 4 + r;
                const float bv = W_b[co];
#pragma unroll
                for (int nt = 0; nt < 2; ++nt) {
                    const int n = n0 + nt * 16 + l15;
                    const size_t a = ((size_t)b * COd + co) * NN + n;
                    out[a] = gm * (acc[cot][nt][r] + bv) + x[a];
                }
            }
    };

    f32x4 acc0[2][2];
    mfma_pass(acc0);
    __syncthreads();          // all waves done reading wbuf half 0
    stage_w(1);               // issue half-1 writes ...
    store_pass(acc0, 0);      // ... overlapped with half-0 stores
    __syncthreads();          // drain half-1 ds_writes
    f32x4 acc1[2][2];
    mfma_pass(acc1);
    store_pass(acc1, 1);
}

// ---------------------------------------------------------------------------
extern "C" void kernel_launch(void* const* d_in, const int* in_sizes, int n_in,
                              void* d_out, int out_size, void* d_ws, size_t ws_size,
                              hipStream_t stream)
{
    const float* x     = (const float*)d_in[0];
    const float* y     = (const float*)d_in[1];
    const float* fk_w  = (const float*)d_in[2];
    const float* fk_g  = (const float*)d_in[3];
    const float* fk_b  = (const float*)d_in[4];
    const float* fk_m  = (const float*)d_in[5];
    const float* fk_v  = (const float*)d_in[6];
    const float* fq_w  = (const float*)d_in[7];
    const float* fq_g  = (const float*)d_in[8];
    const float* fq_b  = (const float*)d_in[9];
    const float* fq_m  = (const float*)d_in[10];
    const float* fq_v  = (const float*)d_in[11];
    const float* fv_w  = (const float*)d_in[12];
    const float* fv_b  = (const float*)d_in[13];
    const float* W_w   = (const float*)d_in[14];
    const float* W_b   = (const float*)d_in[15];
    const float* gamma = (const float*)d_in[16];
    float* out = (float*)d_out;

    char* ws = (char*)d_ws;
    size_t off = 0;
    auto carve = [&](size_t bytes) -> char* {
        char* p = ws + off;
        off = (off + bytes + 255) & ~(size_t)255;
        return p;
    };

    bf16*  kb   = (bf16*)carve((size_t)NB * NN * CKd * 2);
    bf16*  qbuf = (bf16*)carve((size_t)NB * NN * CKd * 2);
    bf16*  vb   = (bf16*)carve((size_t)NB * CVd * NN * 2);

    const size_t region = ws_size - off;
    const size_t per_ks = (size_t)NB * NN * CVd * 2 + (size_t)NB * NN * 4 + 512;
    int KS = 1;
    {
        const int cand[4] = {5, 4, 2, 1};
        for (int i = 0; i < 4; ++i)
            if ((size_t)cand[i] * per_ks <= region) { KS = cand[i]; break; }
    }
    bf16*  pO = (bf16*)carve((size_t)KS * NB * NN * CVd * 2);
    float* pl = (float*)carve((size_t)KS * NB * NN * 4);

    const dim3 blk(256);
    projkqv_kernel<<<dim3(100, 4, NB), blk, 0, stream>>>(x, y,
                                                         fk_w, fk_g, fk_b, fk_m, fk_v,
                                                         fq_w, fq_g, fq_b, fq_m, fq_v,
                                                         fv_w, fv_b, kb, qbuf, vb);
    attn_kernel<<<dim3(100 * NB * KS), blk, 0, stream>>>(qbuf, kb, vb, pO, pl, KS);
    outproj_kernel<<<dim3(200, NB), blk, 0, stream>>>(pO, pl, W_w, W_b, x, gamma, out, KS);
}